// Round 11
// baseline (198.915 us; speedup 1.0000x reference)
//
#include <hip/hip_runtime.h>

#define BB 64
#define LL 512
#define TT 52
#define START_TAG 50
#define END_TAG 51
#define CH 32               // steps per chunk
#define CF (CH * TT)        // floats per f-chunk = 1664
#define PW 64               // P-window slot width (padded, 16B-aligned rows)

typedef __attribute__((ext_vector_type(2))) float f32x2;

__device__ __forceinline__ f32x2 pkmax(f32x2 a, f32x2 b) {
    f32x2 r; r[0] = fmaxf(a[0], b[0]); r[1] = fmaxf(a[1], b[1]); return r;
}

// R19: R18 (verified, 142us dispatch) + explicit issue-order partitioning of
// the serial step so q consumption overlaps the 13-read broadcast pipeline.
// Ledger: 665 cy/step = ~190 cy VALU issue (matches static count) + ~470 cy
// DS wait. If the compiler drains all 14 DS ops before the first q use,
// ~150 cy of read-service time is serialized that could overlap compute.
// sched_barrier(0) partitions force: [loads] [fc2 shadow-fill] [q groups in
// arrival order, m[k] = pkmax(bv[2k],bv[2k+1]) needs ONLY q[k]] [tail tree].
// Compiler inserts precise graded lgkmcnt per partition (no asm waits -> no
// rule-18 hazard). All arithmetic bit-identical to R18 (fc2 hoist preserves
// op order (f+c)+P; same max-tree associations).
// Decision rule: neutral result => step is at its structural floor (RAW
// write->read round trip + broadcast service + issue) => declare ceiling.
// Structure (verified R13..R18): wave 0 serial recurrence, same-address b128
// broadcast of the P window it publishes anyway, setprio(3); waves 1-7 trail
// one chunk recomputing backpointers from the same staged bits (first value-
// match == jnp.argmax) and staging f. Sources pruned to 0..49 (trans[:,50]=
// trans[51,:]=-1000 => never the max). f window mod-4, P window mod-3. One
// barrier per 32 steps.
__launch_bounds__(512, 1)
__global__ void viterbi_kernel(const float* __restrict__ feats,
                               const int* __restrict__ mask,
                               const float* __restrict__ trans,
                               int* __restrict__ out) {
    const int b    = blockIdx.x;
    const int tid  = threadIdx.x;
    const int lane = tid & 63;
    const int w    = tid >> 6;

    __shared__ __align__(16) float s_feat[4][CF];      // f chunks, quad-buffered
    __shared__ __align__(16) float s_pwin[3][CH + 1][PW]; // P history window
    __shared__ unsigned char s_bp[LL * TT];            // backpointers
    __shared__ float s_tr[TT * TT];                    // transitions copy
    __shared__ int s_tags[LL];                         // decode
    __shared__ unsigned char s_map[8 * 52];
    __shared__ int s_ent[9];

    // ---- length n = sum(mask[b,:]) ----
    int partial = 0;
    const int* mrow = mask + b * LL;
    #pragma unroll
    for (int k = 0; k < LL / 64; ++k) partial += mrow[lane + 64 * k];
    #pragma unroll
    for (int off = 32; off >= 1; off >>= 1) partial += __shfl_xor(partial, off, 64);
    const int n = partial;            // uniform, in [256, 512]
    const int H = (n + CH - 1) / CH;  // chunks

    const int flane = (lane < TT) ? lane : (TT - 1);
    const float* frow = feats + (size_t)b * LL * TT;

    s_tags[tid] = 0;

    // ---- stage trans + f chunks 0,1 ----
    for (int e = tid; e < TT * TT; e += 512) s_tr[e] = trans[e];
    for (int e = tid; e < CF; e += 512) {
        s_feat[0][e] = frow[e];
        s_feat[1][e] = frow[CF + e];
    }

    // ---- P0 (wave 0) -> seed the P-window ----
    float bestP = -3.0e38f;
    if (w == 0) {
        bestP = (lane < TT) ? (frow[lane] + trans[START_TAG * TT + lane]) : -3.0e38f;
        s_pwin[0][1][lane] = bestP;   // P_0 at chunk-0 slot 1 (pad lanes harmless)
    }
    __syncthreads();   // staging + P0 visible

    // ---- wave-0 gets arbitration priority for the whole kernel ----
    if (w == 0) __builtin_amdgcn_s_setprio(3);

    // ---- every wave: transition-column pairs in registers (sources 0..49) ----
    f32x2 creg2[25];
    #pragma unroll
    for (int p = 0; p < 25; ++p) {
        creg2[p][0] = s_tr[(2 * p) * TT + flane];       // lane-consecutive, conflict-free
        creg2[p][1] = s_tr[(2 * p + 1) * TT + flane];
    }
    float tE = 0.0f, fcur = 0.0f;
    if (w == 0) {
        tE   = s_tr[flane * TT + END_TAG];
        fcur = s_feat[0][1 * TT + flane];               // f for t=1
    }

    // ---- main loop: chunks of 32 steps, one barrier per chunk ----
    for (int h = 0; h < H; ++h) {
        if (w == 0) {
            // ======== forward chunk h (serial recurrence) ===================
            float* pbase = &s_pwin[h % 3][0][0];
            const int tsta = (h == 0) ? 1 : CH * h;
            const int tend = (CH * (h + 1) < n) ? CH * (h + 1) : n;
            for (int t = tsta; t < tend; ++t) {
                const int slot = t - CH * h;            // P_{t-1} slot; write slot+1

                // P1: broadcast P_{t-1}: 13 x float4, all lanes same address;
                //     then fnx (14th op, consumed next iter at lgkmcnt(13)).
                const float4* prow = (const float4*)(pbase + slot * PW);
                float4 q[13];
                #pragma unroll
                for (int k = 0; k < 13; ++k) q[k] = prow[k];
                int tn = t + 1; if (tn > n - 1) tn = n - 1;
                float fnx = s_feat[(tn >> 5) & 3][(tn & (CH - 1)) * TT + flane];
                __builtin_amdgcn_sched_barrier(0);

                // P2: q-independent fc2 fills the read-latency shadow
                f32x2 fcur2; fcur2[0] = fcur; fcur2[1] = fcur;
                f32x2 fc2[25];
                #pragma unroll
                for (int p = 0; p < 25; ++p) fc2[p] = fcur2 + creg2[p];
                __builtin_amdgcn_sched_barrier(0);

                // m[k] needs ONLY q[k]: consume in arrival order.
                f32x2 m[13];
                #define MGRP(k) { f32x2 qa, qb;                                  \
                    qa[0] = q[k].x; qa[1] = q[k].y;                              \
                    qb[0] = q[k].z; qb[1] = q[k].w;                              \
                    f32x2 ba = fc2[2 * (k)] + qa;      /* v_pk_add_f32 */        \
                    f32x2 bb = fc2[2 * (k) + 1] + qb;                            \
                    m[k] = pkmax(ba, bb); }

                // P3: q[0..3]
                MGRP(0) MGRP(1) MGRP(2) MGRP(3)
                __builtin_amdgcn_sched_barrier(0);
                // P4: q[4..6] + early tree
                MGRP(4) MGRP(5) MGRP(6)
                f32x2 r0 = pkmax(m[0], m[1]);
                f32x2 r1 = pkmax(m[2], m[3]);
                __builtin_amdgcn_sched_barrier(0);
                // P5: q[7..9] + tree
                MGRP(7) MGRP(8) MGRP(9)
                f32x2 r2 = pkmax(m[4], m[5]);
                __builtin_amdgcn_sched_barrier(0);
                // P6: q[10..12] + finish. m[12] = bv2[24] only (50 sources).
                MGRP(10) MGRP(11)
                {
                    f32x2 qa; qa[0] = q[12].x; qa[1] = q[12].y;
                    m[12] = fc2[24] + qa;
                }
                f32x2 r3 = pkmax(m[6], m[7]);
                f32x2 r4 = pkmax(m[8], m[9]);
                f32x2 r5 = pkmax(m[10], m[11]);
                f32x2 r6 = m[12];
                f32x2 u0 = pkmax(pkmax(r0, r1), pkmax(r2, r3));
                f32x2 u1 = pkmax(pkmax(r4, r5), r6);
                f32x2 uf = pkmax(u0, u1);
                float M  = fmaxf(uf[0], uf[1]);
                #undef MGRP

                bestP = M;
                pbase[(slot + 1) * PW + lane] = M;      // publish P_t
                fcur = fnx;
            }
            // chunk-boundary: P_{CH(h+1)-1} is slot 0 of buffer (h+1)%3
            if (tend == CH * (h + 1) && tend < n)
                s_pwin[(h + 1) % 3][0][lane] = bestP;
        } else {
            const int tid2 = tid - 64;   // 0..447
            // ======== stage f chunk h+2 into buffer (h+2)%4 ================
            if (CH * (h + 2) < n) {
                const float* sp = frow + (size_t)CH * (h + 2) * TT;
                float* dp = s_feat[(h + 2) & 3];
                for (int e = tid2; e < CF; e += 448) dp[e] = sp[e];
            }
            // ======== recompute backpointers for chunk h-1 ==================
            // wave w handles t = tsta + (w-1) + 7k; lane j = column j.
            if (h >= 1) {
                const int hh   = h - 1;
                const int tsta = (hh == 0) ? 1 : CH * hh;
                const int tend = (CH * (hh + 1) < n) ? CH * (hh + 1) : n;
                const float* fbuf = s_feat[hh & 3];
                const float* pbuf = &s_pwin[hh % 3][0][0];
                for (int t = tsta + (w - 1); t < tend; t += 7) {
                    const int slotPrev = t - CH * hh;
                    const float4* prow = (const float4*)(pbuf + slotPrev * PW);
                    float4 q[13];
                    #pragma unroll
                    for (int k = 0; k < 13; ++k) q[k] = prow[k];   // broadcast
                    float fv = fbuf[(t & (CH - 1)) * TT + flane];  // consecutive
                    float Mv = pbuf[(slotPrev + 1) * PW + flane];  // consecutive

                    f32x2 fv2; fv2[0] = fv; fv2[1] = fv;
                    f32x2 bv2[25];
                    #pragma unroll
                    for (int p = 0; p < 25; ++p) {
                        f32x2 qq;
                        if ((p & 1) == 0) { qq[0] = q[p >> 1].x; qq[1] = q[p >> 1].y; }
                        else              { qq[0] = q[p >> 1].z; qq[1] = q[p >> 1].w; }
                        f32x2 fc2 = fv2 + creg2[p];     // IDENTICAL op order to wave 0
                        bv2[p] = fc2 + qq;
                    }
                    int idx = 0;
                    #pragma unroll
                    for (int p = 24; p >= 0; --p) {     // smallest matching i wins
                        idx = (bv2[p][1] == Mv) ? (2 * p + 1) : idx;
                        idx = (bv2[p][0] == Mv) ? (2 * p)     : idx;
                    }
                    if (lane < TT) s_bp[t * TT + lane] = (unsigned char)idx;
                }
            }
        }
        __syncthreads();
    }

    // ---- tail: ptr0 (wave 0) and the last chunk's backpointers (others) ----
    if (w == 0) {
        float lv = (lane < TT) ? (bestP + tE) : -3.0e38f;
        int li = lane;
        #pragma unroll
        for (int off = 32; off >= 1; off >>= 1) {
            float ov = __shfl_xor(lv, off, 64);
            int   oi = __shfl_xor(li, off, 64);
            if (ov > lv || (ov == lv && oi < li)) { lv = ov; li = oi; }
        }
        if (tid == 0) s_ent[8] = li;
        __builtin_amdgcn_s_setprio(0);
    } else {
        const int hh   = H - 1;
        const int tsta = (hh == 0) ? 1 : CH * hh;
        const int tend = n;
        const float* fbuf = s_feat[hh & 3];
        const float* pbuf = &s_pwin[hh % 3][0][0];
        for (int t = tsta + (w - 1); t < tend; t += 7) {
            const int slotPrev = t - CH * hh;
            const float4* prow = (const float4*)(pbuf + slotPrev * PW);
            float4 q[13];
            #pragma unroll
            for (int k = 0; k < 13; ++k) q[k] = prow[k];
            float fv = fbuf[(t & (CH - 1)) * TT + flane];
            float Mv = pbuf[(slotPrev + 1) * PW + flane];

            f32x2 fv2; fv2[0] = fv; fv2[1] = fv;
            f32x2 bv2[25];
            #pragma unroll
            for (int p = 0; p < 25; ++p) {
                f32x2 qq;
                if ((p & 1) == 0) { qq[0] = q[p >> 1].x; qq[1] = q[p >> 1].y; }
                else              { qq[0] = q[p >> 1].z; qq[1] = q[p >> 1].w; }
                f32x2 fc2 = fv2 + creg2[p];
                bv2[p] = fc2 + qq;
            }
            int idx = 0;
            #pragma unroll
            for (int p = 24; p >= 0; --p) {
                idx = (bv2[p][1] == Mv) ? (2 * p + 1) : idx;
                idx = (bv2[p][0] == Mv) ? (2 * p)     : idx;
            }
            if (lane < TT) s_bp[t * TT + lane] = (unsigned char)idx;
        }
    }
    __syncthreads();

    const int ptr0 = s_ent[8];

    // ---- backtrace: 8-chunk two-phase parallel pointer chase (512 thr) ----
    const int W  = n - 1;
    const int Sc = (W + 7) >> 3;
    if (tid < 416) {
        int k = tid / 52, y = tid - k * 52;
        int s0 = k * Sc, s1 = min(s0 + Sc, W);
        int x = y;
        for (int s = s0; s < s1; ++s) x = s_bp[(n - 1 - s) * TT + x];
        s_map[k * 52 + y] = (unsigned char)x;
    }
    __syncthreads();
    if (tid == 0) {
        int e = ptr0; s_ent[0] = e;
        #pragma unroll
        for (int k = 1; k < 8; ++k) { e = s_map[(k - 1) * 52 + e]; s_ent[k] = e; }
        s_tags[n - 1] = ptr0;
        s_tags[LL - 1] = ptr0;   // reference quirk: decode[L-1] = pointer0 always
    }
    __syncthreads();
    if (tid < 8) {
        int k = tid;
        int x = s_ent[k];
        int ss0 = k * Sc, ss1 = min(ss0 + Sc, W);
        for (int s = ss0; s < ss1; ++s) {
            x = s_bp[(n - 1 - s) * TT + x];
            s_tags[n - 2 - s] = x;
        }
    }
    __syncthreads();

    // ---- coalesced output write ----
    out[b * LL + tid] = s_tags[tid];
}

extern "C" void kernel_launch(void* const* d_in, const int* in_sizes, int n_in,
                              void* d_out, int out_size, void* d_ws, size_t ws_size,
                              hipStream_t stream) {
    const float* feats = (const float*)d_in[0];
    const int*   mask  = (const int*)d_in[1];
    const float* trans = (const float*)d_in[2];
    int* out = (int*)d_out;
    viterbi_kernel<<<dim3(BB), dim3(512), 0, stream>>>(feats, mask, trans, out);
}

// Round 12
// 195.662 us; speedup vs baseline: 1.0166x; 1.0166x over previous
//
#include <hip/hip_runtime.h>

#define BB 64
#define LL 512
#define TT 52
#define START_TAG 50
#define END_TAG 51
#define CH 32               // steps per chunk
#define CF (CH * TT)        // floats per f-chunk = 1664
#define PW 64               // P-window slot width (padded, 16B-aligned rows)

typedef __attribute__((ext_vector_type(2))) float f32x2;

__device__ __forceinline__ float max3f(float a, float b, float c) {
    return fmaxf(fmaxf(a, b), c);   // fuses to v_max3_f32
}
__device__ __forceinline__ f32x2 pkmax(f32x2 a, f32x2 b) {
    f32x2 r; r[0] = fmaxf(a[0], b[0]); r[1] = fmaxf(a[1], b[1]); return r;
}

// R20 = R18 verbatim (best verified: 142us dispatch, absmax 0.0).
// R19's issue-order partitioning was neutral (145.6) => per the pre-committed
// decision rule, the serial step is at this structure's floor:
//   ~190cy VALU issue + ~85cy DS issue + ~300-375cy exposed RAW round trip
//   (write P_t -> 13x same-address ds_read_b128 broadcast of the value just
//   computed). The round trip IS the algorithm: reads of P_t cannot issue
//   before P_t exists. Scheduling levers measured and exhausted:
//   R16 fence (0), R18 setprio+pk (-6us), R19 partitions (+3.6us).
// Broadcast implementations measured: barrier+LDS 975cy/step (R8),
// replicate 1500 (R9/R10), readlane 1140 (R13), bpermute 2190 (R14),
// same-address b128 broadcast 665 (R15-R19, this kernel).
// Structure: wave 0 runs the serial recurrence alone (pk-add/pk-max,
// sources pruned to 0..49 since trans[:,50]=trans[51,:]=-1000 can never be
// the max); waves 1-7 trail one chunk, recomputing backpointers from the
// SAME staged bits (identical op order => bit-identical bv; first value-
// match == jnp.argmax first-max-wins) and staging f chunks. f window mod-4
// (users h,h+1,h+2,h-1), P window mod-3 (users h,h+1,h-1). One barrier per
// 32 steps. Two-phase 512-wide parallel backtrace.
__launch_bounds__(512, 1)
__global__ void viterbi_kernel(const float* __restrict__ feats,
                               const int* __restrict__ mask,
                               const float* __restrict__ trans,
                               int* __restrict__ out) {
    const int b    = blockIdx.x;
    const int tid  = threadIdx.x;
    const int lane = tid & 63;
    const int w    = tid >> 6;

    __shared__ __align__(16) float s_feat[4][CF];      // f chunks, quad-buffered
    __shared__ __align__(16) float s_pwin[3][CH + 1][PW]; // P history window
    __shared__ unsigned char s_bp[LL * TT];            // backpointers
    __shared__ float s_tr[TT * TT];                    // transitions copy
    __shared__ int s_tags[LL];                         // decode
    __shared__ unsigned char s_map[8 * 52];
    __shared__ int s_ent[9];

    // ---- length n = sum(mask[b,:]) ----
    int partial = 0;
    const int* mrow = mask + b * LL;
    #pragma unroll
    for (int k = 0; k < LL / 64; ++k) partial += mrow[lane + 64 * k];
    #pragma unroll
    for (int off = 32; off >= 1; off >>= 1) partial += __shfl_xor(partial, off, 64);
    const int n = partial;            // uniform, in [256, 512]
    const int H = (n + CH - 1) / CH;  // chunks

    const int flane = (lane < TT) ? lane : (TT - 1);
    const float* frow = feats + (size_t)b * LL * TT;

    s_tags[tid] = 0;

    // ---- stage trans + f chunks 0,1 ----
    for (int e = tid; e < TT * TT; e += 512) s_tr[e] = trans[e];
    for (int e = tid; e < CF; e += 512) {
        s_feat[0][e] = frow[e];
        s_feat[1][e] = frow[CF + e];
    }

    // ---- P0 (wave 0) -> seed the P-window ----
    float bestP = -3.0e38f;
    if (w == 0) {
        bestP = (lane < TT) ? (frow[lane] + trans[START_TAG * TT + lane]) : -3.0e38f;
        s_pwin[0][1][lane] = bestP;   // P_0 at chunk-0 slot 1 (pad lanes harmless)
    }
    __syncthreads();   // staging + P0 visible

    // ---- wave-0 gets DS-pipe arbitration priority for the whole kernel ----
    if (w == 0) __builtin_amdgcn_s_setprio(3);

    // ---- every wave: transition-column pairs in registers (sources 0..49) ----
    f32x2 creg2[25];
    #pragma unroll
    for (int p = 0; p < 25; ++p) {
        creg2[p][0] = s_tr[(2 * p) * TT + flane];       // lane-consecutive, conflict-free
        creg2[p][1] = s_tr[(2 * p + 1) * TT + flane];
    }
    float tE = 0.0f, fcur = 0.0f;
    if (w == 0) {
        tE   = s_tr[flane * TT + END_TAG];
        fcur = s_feat[0][1 * TT + flane];               // f for t=1
    }

    // ---- main loop: chunks of 32 steps, one barrier per chunk ----
    for (int h = 0; h < H; ++h) {
        if (w == 0) {
            // ======== forward chunk h (serial recurrence) ===================
            float* pbase = &s_pwin[h % 3][0][0];
            const int tsta = (h == 0) ? 1 : CH * h;
            const int tend = (CH * (h + 1) < n) ? CH * (h + 1) : n;
            for (int t = tsta; t < tend; ++t) {
                const int slot = t - CH * h;            // P_{t-1} slot; write slot+1

                // broadcast P_{t-1}: 13 x float4, all lanes same address
                const float4* prow = (const float4*)(pbase + slot * PW);
                float4 q[13];
                #pragma unroll
                for (int k = 0; k < 13; ++k) q[k] = prow[k];

                int tn = t + 1; if (tn > n - 1) tn = n - 1;
                float fnx = s_feat[(tn >> 5) & 3][(tn & (CH - 1)) * TT + flane];

                __builtin_amdgcn_sched_barrier(0);      // loads above, compute below

                // bv[i] = (f + c[i]) + P[i], i = 0..49, packed pairs
                f32x2 fcur2; fcur2[0] = fcur; fcur2[1] = fcur;
                f32x2 bv2[25];
                #pragma unroll
                for (int p = 0; p < 25; ++p) {
                    f32x2 qq;
                    if ((p & 1) == 0) { qq[0] = q[p >> 1].x; qq[1] = q[p >> 1].y; }
                    else              { qq[0] = q[p >> 1].z; qq[1] = q[p >> 1].w; }
                    f32x2 fc2 = fcur2 + creg2[p];       // v_pk_add_f32
                    bv2[p] = fc2 + qq;                  // v_pk_add_f32
                }

                // 50-value max tree, packed (max exact in any order)
                f32x2 m[13];
                #pragma unroll
                for (int g = 0; g < 12; ++g) m[g] = pkmax(bv2[2 * g], bv2[2 * g + 1]);
                m[12] = bv2[24];
                f32x2 r[7];
                #pragma unroll
                for (int g = 0; g < 6; ++g) r[g] = pkmax(m[2 * g], m[2 * g + 1]);
                r[6] = m[12];
                f32x2 u0 = pkmax(pkmax(r[0], r[1]), pkmax(r[2], r[3]));
                f32x2 u1 = pkmax(pkmax(r[4], r[5]), r[6]);
                f32x2 uf = pkmax(u0, u1);
                float M  = fmaxf(uf[0], uf[1]);

                bestP = M;
                pbase[(slot + 1) * PW + lane] = M;      // publish P_t
                fcur = fnx;
            }
            // chunk-boundary: P_{CH(h+1)-1} is slot 0 of buffer (h+1)%3
            if (tend == CH * (h + 1) && tend < n)
                s_pwin[(h + 1) % 3][0][lane] = bestP;
        } else {
            const int tid2 = tid - 64;   // 0..447
            // ======== stage f chunk h+2 into buffer (h+2)%4 ================
            if (CH * (h + 2) < n) {
                const float* sp = frow + (size_t)CH * (h + 2) * TT;
                float* dp = s_feat[(h + 2) & 3];
                for (int e = tid2; e < CF; e += 448) dp[e] = sp[e];
            }
            // ======== recompute backpointers for chunk h-1 ==================
            // wave w handles t = tsta + (w-1) + 7k; lane j = column j.
            if (h >= 1) {
                const int hh   = h - 1;
                const int tsta = (hh == 0) ? 1 : CH * hh;
                const int tend = (CH * (hh + 1) < n) ? CH * (hh + 1) : n;
                const float* fbuf = s_feat[hh & 3];
                const float* pbuf = &s_pwin[hh % 3][0][0];
                for (int t = tsta + (w - 1); t < tend; t += 7) {
                    const int slotPrev = t - CH * hh;
                    const float4* prow = (const float4*)(pbuf + slotPrev * PW);
                    float4 q[13];
                    #pragma unroll
                    for (int k = 0; k < 13; ++k) q[k] = prow[k];   // broadcast
                    float fv = fbuf[(t & (CH - 1)) * TT + flane];  // consecutive
                    float Mv = pbuf[(slotPrev + 1) * PW + flane];  // consecutive

                    f32x2 fv2; fv2[0] = fv; fv2[1] = fv;
                    f32x2 bv2[25];
                    #pragma unroll
                    for (int p = 0; p < 25; ++p) {
                        f32x2 qq;
                        if ((p & 1) == 0) { qq[0] = q[p >> 1].x; qq[1] = q[p >> 1].y; }
                        else              { qq[0] = q[p >> 1].z; qq[1] = q[p >> 1].w; }
                        f32x2 fc2 = fv2 + creg2[p];     // IDENTICAL op order to wave 0
                        bv2[p] = fc2 + qq;
                    }
                    int idx = 0;
                    #pragma unroll
                    for (int p = 24; p >= 0; --p) {     // smallest matching i wins
                        idx = (bv2[p][1] == Mv) ? (2 * p + 1) : idx;
                        idx = (bv2[p][0] == Mv) ? (2 * p)     : idx;
                    }
                    if (lane < TT) s_bp[t * TT + lane] = (unsigned char)idx;
                }
            }
        }
        __syncthreads();
    }

    // ---- tail: ptr0 (wave 0) and the last chunk's backpointers (others) ----
    if (w == 0) {
        float lv = (lane < TT) ? (bestP + tE) : -3.0e38f;
        int li = lane;
        #pragma unroll
        for (int off = 32; off >= 1; off >>= 1) {
            float ov = __shfl_xor(lv, off, 64);
            int   oi = __shfl_xor(li, off, 64);
            if (ov > lv || (ov == lv && oi < li)) { lv = ov; li = oi; }
        }
        if (tid == 0) s_ent[8] = li;
        __builtin_amdgcn_s_setprio(0);
    } else {
        const int hh   = H - 1;
        const int tsta = (hh == 0) ? 1 : CH * hh;
        const int tend = n;
        const float* fbuf = s_feat[hh & 3];
        const float* pbuf = &s_pwin[hh % 3][0][0];
        for (int t = tsta + (w - 1); t < tend; t += 7) {
            const int slotPrev = t - CH * hh;
            const float4* prow = (const float4*)(pbuf + slotPrev * PW);
            float4 q[13];
            #pragma unroll
            for (int k = 0; k < 13; ++k) q[k] = prow[k];
            float fv = fbuf[(t & (CH - 1)) * TT + flane];
            float Mv = pbuf[(slotPrev + 1) * PW + flane];

            f32x2 fv2; fv2[0] = fv; fv2[1] = fv;
            f32x2 bv2[25];
            #pragma unroll
            for (int p = 0; p < 25; ++p) {
                f32x2 qq;
                if ((p & 1) == 0) { qq[0] = q[p >> 1].x; qq[1] = q[p >> 1].y; }
                else              { qq[0] = q[p >> 1].z; qq[1] = q[p >> 1].w; }
                f32x2 fc2 = fv2 + creg2[p];
                bv2[p] = fc2 + qq;
            }
            int idx = 0;
            #pragma unroll
            for (int p = 24; p >= 0; --p) {
                idx = (bv2[p][1] == Mv) ? (2 * p + 1) : idx;
                idx = (bv2[p][0] == Mv) ? (2 * p)     : idx;
            }
            if (lane < TT) s_bp[t * TT + lane] = (unsigned char)idx;
        }
    }
    __syncthreads();

    const int ptr0 = s_ent[8];

    // ---- backtrace: 8-chunk two-phase parallel pointer chase (512 thr) ----
    const int W  = n - 1;
    const int Sc = (W + 7) >> 3;
    if (tid < 416) {
        int k = tid / 52, y = tid - k * 52;
        int s0 = k * Sc, s1 = min(s0 + Sc, W);
        int x = y;
        for (int s = s0; s < s1; ++s) x = s_bp[(n - 1 - s) * TT + x];
        s_map[k * 52 + y] = (unsigned char)x;
    }
    __syncthreads();
    if (tid == 0) {
        int e = ptr0; s_ent[0] = e;
        #pragma unroll
        for (int k = 1; k < 8; ++k) { e = s_map[(k - 1) * 52 + e]; s_ent[k] = e; }
        s_tags[n - 1] = ptr0;
        s_tags[LL - 1] = ptr0;   // reference quirk: decode[L-1] = pointer0 always
    }
    __syncthreads();
    if (tid < 8) {
        int k = tid;
        int x = s_ent[k];
        int ss0 = k * Sc, ss1 = min(ss0 + Sc, W);
        for (int s = ss0; s < ss1; ++s) {
            x = s_bp[(n - 1 - s) * TT + x];
            s_tags[n - 2 - s] = x;
        }
    }
    __syncthreads();

    // ---- coalesced output write ----
    out[b * LL + tid] = s_tags[tid];
}

extern "C" void kernel_launch(void* const* d_in, const int* in_sizes, int n_in,
                              void* d_out, int out_size, void* d_ws, size_t ws_size,
                              hipStream_t stream) {
    const float* feats = (const float*)d_in[0];
    const int*   mask  = (const int*)d_in[1];
    const float* trans = (const float*)d_in[2];
    int* out = (int*)d_out;
    viterbi_kernel<<<dim3(BB), dim3(512), 0, stream>>>(feats, mask, trans, out);
}